// Round 7
// baseline (184.560 us; speedup 1.0000x reference)
//
#include <hip/hip_runtime.h>

#define NB 8
#define NT 2048
#define NC 1024
#define NH 64
#define BT (NB*NT)

typedef __bf16 bf16x8 __attribute__((ext_vector_type(8)));
typedef float  f32x4  __attribute__((ext_vector_type(4)));
typedef unsigned short us8 __attribute__((ext_vector_type(8)));

__device__ __forceinline__ unsigned short f2bf(float f) {
  unsigned u = __builtin_bit_cast(unsigned, f);
  u = (u + 0x7FFFu + ((u >> 16) & 1u)) >> 16;   // RNE
  return (unsigned short)u;
}

__device__ __forceinline__ bf16x8 ld_frag(const unsigned short* p) {
  return __builtin_bit_cast(bf16x8, *(const us8*)p);
}

// ---------------------------------------------------------------------------
// Kernel 0: W -> bf16 transposed Wt[192][1024] (row = mat*64+h; 0:q 1:k 2:v).
// ---------------------------------------------------------------------------
__global__ __launch_bounds__(256) void wconv_kernel(
    const float* __restrict__ Wk, const float* __restrict__ Wq,
    const float* __restrict__ Wv, unsigned short* __restrict__ Wt)
{
  __shared__ unsigned short T[64][72];
  const int t = threadIdx.x;
  const int mat = blockIdx.x >> 4;
  const int k0 = (blockIdx.x & 15) * 64;
  const float* __restrict__ W = (mat == 0) ? Wq : (mat == 1) ? Wk : Wv;
  const int kk = t >> 2, h0 = (t & 3) * 16;
  const float* src = &W[(size_t)(k0 + kk) * NH + h0];
#pragma unroll
  for (int j = 0; j < 4; ++j) {
    const float4 v = *(const float4*)(src + j*4);
    T[h0 + j*4 + 0][kk] = f2bf(v.x);
    T[h0 + j*4 + 1][kk] = f2bf(v.y);
    T[h0 + j*4 + 2][kk] = f2bf(v.z);
    T[h0 + j*4 + 3][kk] = f2bf(v.w);
  }
  __syncthreads();
  const int h = t >> 2, c0 = (t & 3) * 16;
  unsigned short* dst = &Wt[(size_t)(mat*64 + h) * NC + k0 + c0];
  *(us8*)dst       = *(const us8*)&T[h][c0];
  *(us8*)(dst + 8) = *(const us8*)&T[h][c0 + 8];
}

// ---------------------------------------------------------------------------
// Kernel 1: fused QKV projection — barrier-free wave-GEMM, no block LDS tile.
// Wave W = blockIdx.x*4 + w owns rows (W>>1)*16 .. +15 and columns
// (W&1)*96 .. +95 (6 n-frags). A-frags straight from x (f32->bf16 native
// cast), B-frags straight from L2-resident Wt. 2048 waves, 0 barriers.
// v (cols 128..191) is transposed through a per-wave LDS buffer so global
// stores are 32B-coalesced rows of vT[h][t].
// ---------------------------------------------------------------------------
__global__ __launch_bounds__(256) void proj_kernel(
    const float* __restrict__ x, const unsigned short* __restrict__ Wt,
    unsigned short* __restrict__ qkv)
{
  __shared__ unsigned short Vb[4][64][18];   // per-wave v-transpose buffer

  const int t = threadIdx.x, w = t >> 6, lane = t & 63;
  const int W = blockIdx.x * 4 + w;
  const int row0 = (W >> 1) * 16;
  const int cb = (W & 1) * 96;
  const int fr = lane & 15, fo = (lane >> 4) * 8, rg = (lane >> 4) * 4;

  f32x4 acc[6];
#pragma unroll
  for (int n = 0; n < 6; ++n) acc[n] = (f32x4){0.f, 0.f, 0.f, 0.f};

  const float* __restrict__ xrow = &x[(size_t)(row0 + fr) * NC];

  for (int k0 = 0; k0 < NC; k0 += 64) {
    bf16x8 af[2];
#pragma unroll
    for (int ks = 0; ks < 2; ++ks) {
      const float* p = xrow + k0 + ks*32 + fo;
      const float4 a = *(const float4*)p;
      const float4 b = *(const float4*)(p + 4);
      bf16x8 v;
      v[0] = (__bf16)a.x; v[1] = (__bf16)a.y; v[2] = (__bf16)a.z; v[3] = (__bf16)a.w;
      v[4] = (__bf16)b.x; v[5] = (__bf16)b.y; v[6] = (__bf16)b.z; v[7] = (__bf16)b.w;
      af[ks] = v;
    }
    bf16x8 bfr[2][6];
#pragma unroll
    for (int ks = 0; ks < 2; ++ks)
#pragma unroll
      for (int n = 0; n < 6; ++n)
        bfr[ks][n] = ld_frag(&Wt[(size_t)(cb + n*16 + fr) * NC + k0 + ks*32 + fo]);
#pragma unroll
    for (int ks = 0; ks < 2; ++ks)
#pragma unroll
      for (int n = 0; n < 6; ++n)
        acc[n] = __builtin_amdgcn_mfma_f32_16x16x32_bf16(af[ks], bfr[ks][n], acc[n], 0, 0, 0);
  }

  // epilogue
#pragma unroll
  for (int n = 0; n < 6; ++n) {
    const int col = cb + n*16;
    if (col < 128) {                         // q (0-63) and k (64-127): natural layout
      const int mat = col >> 6;
      unsigned short* op = qkv + (size_t)mat * BT * NH;
      const int h = (col & 63) + fr;
#pragma unroll
      for (int r = 0; r < 4; ++r)
        op[(size_t)(row0 + rg + r) * NH + h] = f2bf(acc[n][r]);
    } else {                                 // v: stage transposed in per-wave LDS
#pragma unroll
      for (int r = 0; r < 4; ++r)
        Vb[w][(col - 128) + fr][rg + r] = f2bf(acc[n][r]);
    }
  }
  if (cb == 96) {                            // this wave produced v: flush vT rows
    unsigned short* vt = qkv + (size_t)2 * BT * NH;   // vT[64][BT]
    unsigned short* dst = &vt[(size_t)lane * BT + row0];
    *(us8*)dst       = *(const us8*)&Vb[w][lane][0];
    *(us8*)(dst + 8) = *(const us8*)&Vb[w][lane][8];
  }
}

// ---------------------------------------------------------------------------
// Kernel 2: causal attention, fixed-offset softmax (p = exp(s/8), the
// normalization cancels in the final divide). Block = paired q-tiles
// (j, 127-j) -> uniform ~33 kv-tiles. 4 waves, kv-split mod 4. XCD swizzle:
// lin%8 = batch, so each XCD's L2 holds exactly one batch's K+V (512 KB).
// ---------------------------------------------------------------------------
__global__ __launch_bounds__(256) void attn_kernel(
    const unsigned short* __restrict__ qkv, float* __restrict__ out)
{
  __shared__ unsigned short Psm[4][16][72];   // per-wave P tile [qrow][kv]
  __shared__ float co[4][16][68];             // partial O per wave
  __shared__ float cl[4][16];                 // partial denom per wave

  const int t = threadIdx.x, w = t >> 6, lane = t & 63;
  const int lin = blockIdx.x + 64 * blockIdx.y;
  const int b = lin & 7;                      // XCD-affine batch
  const int j0 = lin >> 3;                    // 0..63
  const unsigned short* __restrict__ qp = qkv;
  const unsigned short* __restrict__ kp = qkv + (size_t)BT * NH;
  const unsigned short* __restrict__ vt = qkv + (size_t)2 * BT * NH;
  const int fr = lane & 15, fo = (lane >> 4) * 8, rg = (lane >> 4) * 4;

#pragma unroll 1
  for (int ph = 0; ph < 2; ++ph) {
    const int j = ph ? (127 - j0) : j0;
    const int q0 = j * 16;
    const int ntiles = (j >> 2) + 1;

    bf16x8 aq0, aq1;
    {
      const size_t qoff = ((size_t)b * NT + q0 + fr) * NH;
      aq0 = ld_frag(&qp[qoff + fo]);
      aq1 = ld_frag(&qp[qoff + 32 + fo]);
    }

    f32x4 o[4];
#pragma unroll
    for (int n = 0; n < 4; ++n) o[n] = (f32x4){0.f, 0.f, 0.f, 0.f};
    float lp[4] = {0.f, 0.f, 0.f, 0.f};

    for (int kt = w; kt < ntiles; kt += 4) {
      const int kv0 = kt * 64;

      f32x4 s[4];
#pragma unroll
      for (int n = 0; n < 4; ++n) s[n] = (f32x4){0.f, 0.f, 0.f, 0.f};
#pragma unroll
      for (int n = 0; n < 4; ++n) {
        const size_t koff = ((size_t)b*NT + kv0 + n*16 + fr) * NH + fo;
        s[n] = __builtin_amdgcn_mfma_f32_16x16x32_bf16(aq0, ld_frag(&kp[koff]), s[n], 0, 0, 0);
        s[n] = __builtin_amdgcn_mfma_f32_16x16x32_bf16(aq1, ld_frag(&kp[koff + 32]), s[n], 0, 0, 0);
      }

#pragma unroll
      for (int n = 0; n < 4; ++n)
#pragma unroll
        for (int r = 0; r < 4; ++r) s[n][r] = __expf(s[n][r] * 0.125f);

      if (kt == ntiles - 1) {
#pragma unroll
        for (int n = 0; n < 4; ++n) {
          const int col = kv0 + n*16 + fr;
#pragma unroll
          for (int r = 0; r < 4; ++r)
            if (col > q0 + rg + r) s[n][r] = 0.f;
        }
      }

#pragma unroll
      for (int r = 0; r < 4; ++r)
        lp[r] += (s[0][r] + s[1][r]) + (s[2][r] + s[3][r]);

#pragma unroll
      for (int n = 0; n < 4; ++n)
#pragma unroll
        for (int r = 0; r < 4; ++r)
          Psm[w][rg + r][n*16 + fr] = f2bf(s[n][r]);

      bf16x8 pa0 = ld_frag(&Psm[w][fr][fo]);
      bf16x8 pa1 = ld_frag(&Psm[w][fr][32 + fo]);

#pragma unroll
      for (int n = 0; n < 4; ++n) {
        const size_t voff = (size_t)(n*16 + fr) * BT + (size_t)b*NT + kv0 + fo;
        o[n] = __builtin_amdgcn_mfma_f32_16x16x32_bf16(pa0, ld_frag(&vt[voff]), o[n], 0, 0, 0);
        o[n] = __builtin_amdgcn_mfma_f32_16x16x32_bf16(pa1, ld_frag(&vt[voff + 32]), o[n], 0, 0, 0);
      }
    }

#pragma unroll
    for (int r = 0; r < 4; ++r) {
#pragma unroll
      for (int off = 1; off < 16; off <<= 1) lp[r] += __shfl_xor(lp[r], off);
    }
    if (fr == 0) {
#pragma unroll
      for (int r = 0; r < 4; ++r) cl[w][rg + r] = lp[r];
    }
#pragma unroll
    for (int n = 0; n < 4; ++n)
#pragma unroll
      for (int r = 0; r < 4; ++r) co[w][rg + r][n*16 + fr] = o[n][r];
    __syncthreads();

    {
      const int row = t >> 4, c0 = (t & 15) * 4;
      const float l = (cl[0][row] + cl[1][row]) + (cl[2][row] + cl[3][row]);
      const float inv = 1.f / l;
      float4 ov;
      ov.x = ((co[0][row][c0+0] + co[1][row][c0+0]) + (co[2][row][c0+0] + co[3][row][c0+0])) * inv;
      ov.y = ((co[0][row][c0+1] + co[1][row][c0+1]) + (co[2][row][c0+1] + co[3][row][c0+1])) * inv;
      ov.z = ((co[0][row][c0+2] + co[1][row][c0+2]) + (co[2][row][c0+2] + co[3][row][c0+2])) * inv;
      ov.w = ((co[0][row][c0+3] + co[1][row][c0+3]) + (co[2][row][c0+3] + co[3][row][c0+3])) * inv;
      *(float4*)&out[((size_t)b*NT + q0 + row) * NH + c0] = ov;
    }
    if (ph == 0) __syncthreads();
  }
}

extern "C" void kernel_launch(void* const* d_in, const int* in_sizes, int n_in,
                              void* d_out, int out_size, void* d_ws, size_t ws_size,
                              hipStream_t stream) {
  (void)in_sizes; (void)n_in; (void)out_size; (void)ws_size;
  const float* x  = (const float*)d_in[0];
  const float* Wk = (const float*)d_in[1];
  const float* Wq = (const float*)d_in[2];
  const float* Wv = (const float*)d_in[3];
  unsigned short* qkv = (unsigned short*)d_ws;                       // q,k natural + vT, 6 MB
  unsigned short* Wt  = qkv + (size_t)3 * BT * NH;                   // 384 KB

  wconv_kernel<<<48, 256, 0, stream>>>(Wk, Wq, Wv, Wt);
  proj_kernel<<<BT/32, 256, 0, stream>>>(x, Wt, qkv);
  attn_kernel<<<dim3(64, NB), 256, 0, stream>>>(qkv, (float*)d_out);
}

// Round 9
// 152.528 us; speedup vs baseline: 1.2100x; 1.2100x over previous
//
#include <hip/hip_runtime.h>

#define NB 8
#define NT 2048
#define NC 1024
#define NH 64
#define BT (NB*NT)

typedef __bf16 bf16x8 __attribute__((ext_vector_type(8)));
typedef float  f32x4  __attribute__((ext_vector_type(4)));
typedef unsigned short us8 __attribute__((ext_vector_type(8)));

__device__ __forceinline__ unsigned short f2bf(float f) {
  unsigned u = __builtin_bit_cast(unsigned, f);
  u = (u + 0x7FFFu + ((u >> 16) & 1u)) >> 16;   // RNE
  return (unsigned short)u;
}

__device__ __forceinline__ bf16x8 ld_frag(const unsigned short* p) {
  return __builtin_bit_cast(bf16x8, *(const us8*)p);
}

// ---------------------------------------------------------------------------
// Kernel 0: W -> bf16 transposed Wt[192][1024] (row = mat*64+h; 0:q 1:k 2:v).
// ---------------------------------------------------------------------------
__global__ __launch_bounds__(256) void wconv_kernel(
    const float* __restrict__ Wk, const float* __restrict__ Wq,
    const float* __restrict__ Wv, unsigned short* __restrict__ Wt)
{
  __shared__ unsigned short T[64][72];
  const int t = threadIdx.x;
  const int mat = blockIdx.x >> 4;
  const int k0 = (blockIdx.x & 15) * 64;
  const float* __restrict__ W = (mat == 0) ? Wq : (mat == 1) ? Wk : Wv;
  const int kk = t >> 2, h0 = (t & 3) * 16;
  const float* src = &W[(size_t)(k0 + kk) * NH + h0];
#pragma unroll
  for (int j = 0; j < 4; ++j) {
    const float4 v = *(const float4*)(src + j*4);
    T[h0 + j*4 + 0][kk] = f2bf(v.x);
    T[h0 + j*4 + 1][kk] = f2bf(v.y);
    T[h0 + j*4 + 2][kk] = f2bf(v.z);
    T[h0 + j*4 + 3][kk] = f2bf(v.w);
  }
  __syncthreads();
  const int h = t >> 2, c0 = (t & 3) * 16;
  unsigned short* dst = &Wt[(size_t)(mat*64 + h) * NC + k0 + c0];
  *(us8*)dst       = *(const us8*)&T[h][c0];
  *(us8*)(dst + 8) = *(const us8*)&T[h][c0 + 8];
}

// ---------------------------------------------------------------------------
// Kernel 1: fused QKV projection. BM=32, BK=64, 256 thr (4 waves), grid 512
// (2 blocks/CU so barriers overlap across blocks). x staged as **f32** with
// dense 1KB-per-instruction coalescing (row = chunk/16), padded LDS; f32->
// bf16 conversion happens at fragment read (v_cvt_pk). B-frags read directly
// from L2-resident Wt. All 4 waves share the 32 A-rows; wave w owns cols
// 48w..48w+47. v (cols>=128) exits via block LDS transpose -> coalesced vT.
// ---------------------------------------------------------------------------
__global__ __launch_bounds__(256) void proj_kernel(
    const float* __restrict__ x, const unsigned short* __restrict__ Wt,
    unsigned short* __restrict__ qkv)
{
  __shared__ float Asmf[32][68];             // [row][k] f32, +4 pad
  __shared__ unsigned short Vb[64][40];      // v-transpose buffer [h][t-chunk]

  const int t = threadIdx.x, w = t >> 6, lane = t & 63;
  const int m0 = blockIdx.x * 32;
  const int fr = lane & 15, fo = (lane >> 4) * 8, rg = (lane >> 4) * 4;

  f32x4 acc[2][3];
#pragma unroll
  for (int m = 0; m < 2; ++m)
#pragma unroll
    for (int n = 0; n < 3; ++n) acc[m][n] = (f32x4){0.f, 0.f, 0.f, 0.f};

  const int srow0 = t >> 4, scol = (t & 15) * 4;     // chunk 1: rows 0-15
  const int srow1 = srow0 + 16;                      // chunk 2: rows 16-31

  for (int k0 = 0; k0 < NC; k0 += 64) {
    { // stage A as f32: two dense 1KB-coalesced float4 loads per thread
      const float4 a = *(const float4*)&x[(size_t)(m0 + srow0) * NC + k0 + scol];
      const float4 b = *(const float4*)&x[(size_t)(m0 + srow1) * NC + k0 + scol];
      *(f32x4*)&Asmf[srow0][scol] = (f32x4){a.x, a.y, a.z, a.w};
      *(f32x4*)&Asmf[srow1][scol] = (f32x4){b.x, b.y, b.z, b.w};
    }
    __syncthreads();

    bf16x8 af[2][2], bfr[2][3];
#pragma unroll
    for (int m = 0; m < 2; ++m)
#pragma unroll
      for (int ks = 0; ks < 2; ++ks) {
        const f32x4 lo = *(const f32x4*)&Asmf[m*16 + fr][ks*32 + fo];
        const f32x4 hi = *(const f32x4*)&Asmf[m*16 + fr][ks*32 + fo + 4];
        bf16x8 v;
        v[0] = (__bf16)lo[0]; v[1] = (__bf16)lo[1]; v[2] = (__bf16)lo[2]; v[3] = (__bf16)lo[3];
        v[4] = (__bf16)hi[0]; v[5] = (__bf16)hi[1]; v[6] = (__bf16)hi[2]; v[7] = (__bf16)hi[3];
        af[m][ks] = v;
      }
#pragma unroll
    for (int ks = 0; ks < 2; ++ks)
#pragma unroll
      for (int n = 0; n < 3; ++n)
        bfr[ks][n] = ld_frag(&Wt[(size_t)(w*48 + n*16 + fr) * NC + k0 + ks*32 + fo]);
#pragma unroll
    for (int ks = 0; ks < 2; ++ks)
#pragma unroll
      for (int m = 0; m < 2; ++m)
#pragma unroll
        for (int n = 0; n < 3; ++n)
          acc[m][n] = __builtin_amdgcn_mfma_f32_16x16x32_bf16(af[m][ks], bfr[ks][n], acc[m][n], 0, 0, 0);
    __syncthreads();
  }

  // epilogue: q,k natural; v staged transposed in LDS then coalesced flush
#pragma unroll
  for (int m = 0; m < 2; ++m)
#pragma unroll
    for (int n = 0; n < 3; ++n) {
      const int col = w*48 + n*16;
      if (col < 128) {
        unsigned short* op = qkv + (size_t)(col >> 6) * BT * NH;
        const int h = (col & 63) + fr;
#pragma unroll
        for (int r = 0; r < 4; ++r)
          op[(size_t)(m0 + m*16 + rg + r) * NH + h] = f2bf(acc[m][n][r]);
      } else {
#pragma unroll
        for (int r = 0; r < 4; ++r)
          Vb[(col - 128) + fr][m*16 + rg + r] = f2bf(acc[m][n][r]);
      }
    }
  __syncthreads();
  { // flush vT[h][m0..m0+31], 16B-coalesced
    unsigned short* vt = qkv + (size_t)2 * BT * NH;
    const int h = t >> 2, c = (t & 3) * 8;
    *(us8*)&vt[(size_t)h * BT + m0 + c] = *(const us8*)&Vb[h][c];
  }
}

// ---------------------------------------------------------------------------
// Kernel 2: causal attention, fixed-offset softmax (p = exp(s/8); the
// normalization cancels in the final divide). Block = 512 thr (8 waves),
// processes q-tiles j and 127-j as two phases; within a phase all 8 waves
// kv-split mod 8 -> per-phase makespan ceil(ntiles/8) is uniform (4-5 total
// rounds for every block). 16 waves/CU (4/SIMD). Grid (64,8)=512 blocks.
// ---------------------------------------------------------------------------
__global__ __launch_bounds__(512) void attn_kernel(
    const unsigned short* __restrict__ qkv, float* __restrict__ out)
{
  __shared__ unsigned short Psm[8][16][72];   // per-wave P tile [qrow][kv]
  __shared__ float co[8][16][68];             // partial O per wave
  __shared__ float cl[8][16];                 // partial denom per wave

  const int t = threadIdx.x, w = t >> 6, lane = t & 63;
  const int lin = blockIdx.x + 64 * blockIdx.y;
  const int b = lin & 7;                      // XCD-affine batch
  const int j0 = lin >> 3;                    // 0..63
  const unsigned short* __restrict__ qp = qkv;
  const unsigned short* __restrict__ kp = qkv + (size_t)BT * NH;
  const unsigned short* __restrict__ vt = qkv + (size_t)2 * BT * NH;
  const int fr = lane & 15, fo = (lane >> 4) * 8, rg = (lane >> 4) * 4;

#pragma unroll 1
  for (int ph = 0; ph < 2; ++ph) {
    const int j = ph ? (127 - j0) : j0;
    const int q0 = j * 16;
    const int ntiles = (j >> 2) + 1;

    bf16x8 aq0, aq1;
    {
      const size_t qoff = ((size_t)b * NT + q0 + fr) * NH;
      aq0 = ld_frag(&qp[qoff + fo]);
      aq1 = ld_frag(&qp[qoff + 32 + fo]);
    }

    f32x4 o[4];
#pragma unroll
    for (int n = 0; n < 4; ++n) o[n] = (f32x4){0.f, 0.f, 0.f, 0.f};
    float lp[4] = {0.f, 0.f, 0.f, 0.f};

    for (int kt = w; kt < ntiles; kt += 8) {
      const int kv0 = kt * 64;

      f32x4 s[4];
#pragma unroll
      for (int n = 0; n < 4; ++n) s[n] = (f32x4){0.f, 0.f, 0.f, 0.f};
#pragma unroll
      for (int n = 0; n < 4; ++n) {
        const size_t koff = ((size_t)b*NT + kv0 + n*16 + fr) * NH + fo;
        s[n] = __builtin_amdgcn_mfma_f32_16x16x32_bf16(aq0, ld_frag(&kp[koff]), s[n], 0, 0, 0);
        s[n] = __builtin_amdgcn_mfma_f32_16x16x32_bf16(aq1, ld_frag(&kp[koff + 32]), s[n], 0, 0, 0);
      }

#pragma unroll
      for (int n = 0; n < 4; ++n)
#pragma unroll
        for (int r = 0; r < 4; ++r) s[n][r] = __expf(s[n][r] * 0.125f);

      if (kt == ntiles - 1) {   // only the last tile is causally partial
#pragma unroll
        for (int n = 0; n < 4; ++n) {
          const int col = kv0 + n*16 + fr;
#pragma unroll
          for (int r = 0; r < 4; ++r)
            if (col > q0 + rg + r) s[n][r] = 0.f;
        }
      }

#pragma unroll
      for (int r = 0; r < 4; ++r)
        lp[r] += (s[0][r] + s[1][r]) + (s[2][r] + s[3][r]);

      // P -> per-wave LDS (C-layout), read back in A-layout (same wave)
#pragma unroll
      for (int n = 0; n < 4; ++n)
#pragma unroll
        for (int r = 0; r < 4; ++r)
          Psm[w][rg + r][n*16 + fr] = f2bf(s[n][r]);

      bf16x8 pa0 = ld_frag(&Psm[w][fr][fo]);
      bf16x8 pa1 = ld_frag(&Psm[w][fr][32 + fo]);

#pragma unroll
      for (int n = 0; n < 4; ++n) {
        const size_t voff = (size_t)(n*16 + fr) * BT + (size_t)b*NT + kv0 + fo;
        o[n] = __builtin_amdgcn_mfma_f32_16x16x32_bf16(pa0, ld_frag(&vt[voff]), o[n], 0, 0, 0);
        o[n] = __builtin_amdgcn_mfma_f32_16x16x32_bf16(pa1, ld_frag(&vt[voff + 32]), o[n], 0, 0, 0);
      }
    }

    // publish per-wave partials
#pragma unroll
    for (int r = 0; r < 4; ++r) {
#pragma unroll
      for (int off = 1; off < 16; off <<= 1) lp[r] += __shfl_xor(lp[r], off);
    }
    if (fr == 0) {
#pragma unroll
      for (int r = 0; r < 4; ++r) cl[w][rg + r] = lp[r];
    }
#pragma unroll
    for (int n = 0; n < 4; ++n)
#pragma unroll
      for (int r = 0; r < 4; ++r) co[w][rg + r][n*16 + fr] = o[n][r];
    __syncthreads();

    { // merge 8 kv-split partials: plain sums (common exponent offset)
      const int row = (t >> 4) & 15, c0 = (t & 15) * 4;
      if (t < 256) {
        float l = 0.f;
#pragma unroll
        for (int ww = 0; ww < 8; ++ww) l += cl[ww][row];
        const float inv = 1.f / l;
        float4 ov = {0.f, 0.f, 0.f, 0.f};
#pragma unroll
        for (int ww = 0; ww < 8; ++ww) {
          ov.x += co[ww][row][c0+0]; ov.y += co[ww][row][c0+1];
          ov.z += co[ww][row][c0+2]; ov.w += co[ww][row][c0+3];
        }
        ov.x *= inv; ov.y *= inv; ov.z *= inv; ov.w *= inv;
        *(float4*)&out[((size_t)b*NT + q0 + row) * NH + c0] = ov;
      }
    }
    if (ph == 0) __syncthreads();
  }
}

extern "C" void kernel_launch(void* const* d_in, const int* in_sizes, int n_in,
                              void* d_out, int out_size, void* d_ws, size_t ws_size,
                              hipStream_t stream) {
  (void)in_sizes; (void)n_in; (void)out_size; (void)ws_size;
  const float* x  = (const float*)d_in[0];
  const float* Wk = (const float*)d_in[1];
  const float* Wq = (const float*)d_in[2];
  const float* Wv = (const float*)d_in[3];
  unsigned short* qkv = (unsigned short*)d_ws;                       // q,k natural + vT, 6 MB
  unsigned short* Wt  = qkv + (size_t)3 * BT * NH;                   // 384 KB

  wconv_kernel<<<48, 256, 0, stream>>>(Wk, Wq, Wv, Wt);
  proj_kernel<<<BT/32, 256, 0, stream>>>(x, Wt, qkv);
  attn_kernel<<<dim3(64, NB), 512, 0, stream>>>(qkv, (float*)d_out);
}

// Round 10
// 147.650 us; speedup vs baseline: 1.2500x; 1.0330x over previous
//
#include <hip/hip_runtime.h>

#define NB 8
#define NT 2048
#define NC 1024
#define NH 64
#define BT (NB*NT)

typedef __bf16 bf16x8 __attribute__((ext_vector_type(8)));
typedef float  f32x4  __attribute__((ext_vector_type(4)));
typedef unsigned short us8 __attribute__((ext_vector_type(8)));

__device__ __forceinline__ unsigned short f2bf(float f) {
  unsigned u = __builtin_bit_cast(unsigned, f);
  u = (u + 0x7FFFu + ((u >> 16) & 1u)) >> 16;   // RNE
  return (unsigned short)u;
}

__device__ __forceinline__ bf16x8 ld_frag(const unsigned short* p) {
  return __builtin_bit_cast(bf16x8, *(const us8*)p);
}

// ---------------------------------------------------------------------------
// Kernel 0: W -> bf16 transposed Wt[192][1024] (row = mat*64+h; 0:q 1:k 2:v).
// ---------------------------------------------------------------------------
__global__ __launch_bounds__(256) void wconv_kernel(
    const float* __restrict__ Wk, const float* __restrict__ Wq,
    const float* __restrict__ Wv, unsigned short* __restrict__ Wt)
{
  __shared__ unsigned short T[64][72];
  const int t = threadIdx.x;
  const int mat = blockIdx.x >> 4;
  const int k0 = (blockIdx.x & 15) * 64;
  const float* __restrict__ W = (mat == 0) ? Wq : (mat == 1) ? Wk : Wv;
  const int kk = t >> 2, h0 = (t & 3) * 16;
  const float* src = &W[(size_t)(k0 + kk) * NH + h0];
#pragma unroll
  for (int j = 0; j < 4; ++j) {
    const float4 v = *(const float4*)(src + j*4);
    T[h0 + j*4 + 0][kk] = f2bf(v.x);
    T[h0 + j*4 + 1][kk] = f2bf(v.y);
    T[h0 + j*4 + 2][kk] = f2bf(v.z);
    T[h0 + j*4 + 3][kk] = f2bf(v.w);
  }
  __syncthreads();
  const int h = t >> 2, c0 = (t & 3) * 16;
  unsigned short* dst = &Wt[(size_t)(mat*64 + h) * NC + k0 + c0];
  *(us8*)dst       = *(const us8*)&T[h][c0];
  *(us8*)(dst + 8) = *(const us8*)&T[h][c0 + 8];
}

// ---------------------------------------------------------------------------
// Kernel 1: fused QKV projection. BM=32, BN=192, BK=64, 256 thr (4 waves).
// A staged as f32 (convert at fragment read); B (Wt) staged in LDS via
// coalesced us8 copies — NO scattered global fragment loads. Both tiles
// double-buffered -> ONE barrier per K-step, stage overlaps MFMA.
// Wave w owns cols 48w..48w+47 (2x3 frags over 32 rows). Grid 512 (2/CU).
// ---------------------------------------------------------------------------
__global__ __launch_bounds__(256) void proj_kernel(
    const float* __restrict__ x, const unsigned short* __restrict__ Wt,
    unsigned short* __restrict__ qkv)
{
  __shared__ float Asmf[2][32][68];            // [buf][row][k] f32, +4 pad
  __shared__ unsigned short Bsm[2][192][72];   // [buf][col'][k] bf16, +8 pad
  __shared__ unsigned short Vb[64][40];        // v-transpose buffer

  const int t = threadIdx.x, w = t >> 6, lane = t & 63;
  const int m0 = blockIdx.x * 32;
  const int fr = lane & 15, fo = (lane >> 4) * 8, rg = (lane >> 4) * 4;

  f32x4 acc[2][3];
#pragma unroll
  for (int m = 0; m < 2; ++m)
#pragma unroll
    for (int n = 0; n < 3; ++n) acc[m][n] = (f32x4){0.f, 0.f, 0.f, 0.f};

  const int srow0 = t >> 4, scol = (t & 15) * 4;     // A: rows 0-15 / 16-31
  const int srow1 = srow0 + 16;
  const int br = t >> 3, bkc = (t & 7) * 8;          // B: 6 chunks of 256 thr

  // stage step 0 into buf 0
  {
    const float4 a = *(const float4*)&x[(size_t)(m0 + srow0) * NC + scol];
    const float4 b = *(const float4*)&x[(size_t)(m0 + srow1) * NC + scol];
    *(f32x4*)&Asmf[0][srow0][scol] = (f32x4){a.x, a.y, a.z, a.w};
    *(f32x4*)&Asmf[0][srow1][scol] = (f32x4){b.x, b.y, b.z, b.w};
#pragma unroll
    for (int i = 0; i < 6; ++i) {
      const int c = t + 256*i, r = (c >> 3) + (i >= 3 ? 96 : 0) - (i >= 3 ? 96 : 0); // r = c>>3
      (void)r;
      const int rr = c >> 3, kc = (c & 7) * 8;
      *(us8*)&Bsm[0][rr][kc] = *(const us8*)&Wt[(size_t)rr * NC + kc];
    }
  }
  __syncthreads();

  for (int s = 0; s < 16; ++s) {
    const int cur = s & 1;
    if (s < 15) {  // stage step s+1 into the other buffer (overlaps MFMA)
      const int k1 = (s + 1) * 64;
      const float4 a = *(const float4*)&x[(size_t)(m0 + srow0) * NC + k1 + scol];
      const float4 b = *(const float4*)&x[(size_t)(m0 + srow1) * NC + k1 + scol];
      *(f32x4*)&Asmf[cur^1][srow0][scol] = (f32x4){a.x, a.y, a.z, a.w};
      *(f32x4*)&Asmf[cur^1][srow1][scol] = (f32x4){b.x, b.y, b.z, b.w};
#pragma unroll
      for (int i = 0; i < 6; ++i) {
        const int c = t + 256*i, rr = c >> 3, kc = (c & 7) * 8;
        *(us8*)&Bsm[cur^1][rr][kc] = *(const us8*)&Wt[(size_t)rr * NC + k1 + kc];
      }
    }

    bf16x8 af[2][2], bfr[2][3];
#pragma unroll
    for (int m = 0; m < 2; ++m)
#pragma unroll
      for (int ks = 0; ks < 2; ++ks) {
        const f32x4 lo = *(const f32x4*)&Asmf[cur][m*16 + fr][ks*32 + fo];
        const f32x4 hi = *(const f32x4*)&Asmf[cur][m*16 + fr][ks*32 + fo + 4];
        bf16x8 v;
        v[0] = (__bf16)lo[0]; v[1] = (__bf16)lo[1]; v[2] = (__bf16)lo[2]; v[3] = (__bf16)lo[3];
        v[4] = (__bf16)hi[0]; v[5] = (__bf16)hi[1]; v[6] = (__bf16)hi[2]; v[7] = (__bf16)hi[3];
        af[m][ks] = v;
      }
#pragma unroll
    for (int ks = 0; ks < 2; ++ks)
#pragma unroll
      for (int n = 0; n < 3; ++n)
        bfr[ks][n] = ld_frag(&Bsm[cur][w*48 + n*16 + fr][ks*32 + fo]);
#pragma unroll
    for (int ks = 0; ks < 2; ++ks)
#pragma unroll
      for (int m = 0; m < 2; ++m)
#pragma unroll
        for (int n = 0; n < 3; ++n)
          acc[m][n] = __builtin_amdgcn_mfma_f32_16x16x32_bf16(af[m][ks], bfr[ks][n], acc[m][n], 0, 0, 0);
    __syncthreads();
  }

  // epilogue: q,k natural; v staged transposed in LDS then coalesced flush
#pragma unroll
  for (int m = 0; m < 2; ++m)
#pragma unroll
    for (int n = 0; n < 3; ++n) {
      const int col = w*48 + n*16;
      if (col < 128) {
        unsigned short* op = qkv + (size_t)(col >> 6) * BT * NH;
        const int h = (col & 63) + fr;
#pragma unroll
        for (int r = 0; r < 4; ++r)
          op[(size_t)(m0 + m*16 + rg + r) * NH + h] = f2bf(acc[m][n][r]);
      } else {
#pragma unroll
        for (int r = 0; r < 4; ++r)
          Vb[(col - 128) + fr][m*16 + rg + r] = f2bf(acc[m][n][r]);
      }
    }
  __syncthreads();
  { // flush vT[h][m0..m0+31], 16B-coalesced
    unsigned short* vt = qkv + (size_t)2 * BT * NH;
    const int h = t >> 2, c = (t & 3) * 8;
    *(us8*)&vt[(size_t)h * BT + m0 + c] = *(const us8*)&Vb[h][c];
  }
}

// ---------------------------------------------------------------------------
// Kernel 2: causal attention, fixed-offset softmax (p = exp(s/8); the
// normalization cancels in the final divide). Block = 512 thr (8 waves),
// q-tiles j and 127-j as two phases, kv-split mod 8 within a phase.
// NO blockIdx remap (the R7 lin&7 remap cost +28 us). Grid (64,8).
// ---------------------------------------------------------------------------
__global__ __launch_bounds__(512) void attn_kernel(
    const unsigned short* __restrict__ qkv, float* __restrict__ out)
{
  __shared__ unsigned short Psm[8][16][72];   // per-wave P tile [qrow][kv]
  __shared__ float co[8][16][68];             // partial O per wave
  __shared__ float cl[8][16];                 // partial denom per wave

  const int t = threadIdx.x, w = t >> 6, lane = t & 63;
  const int b = blockIdx.y;
  const int j0 = blockIdx.x;                  // 0..63
  const unsigned short* __restrict__ qp = qkv;
  const unsigned short* __restrict__ kp = qkv + (size_t)BT * NH;
  const unsigned short* __restrict__ vt = qkv + (size_t)2 * BT * NH;
  const int fr = lane & 15, fo = (lane >> 4) * 8, rg = (lane >> 4) * 4;

#pragma unroll 1
  for (int ph = 0; ph < 2; ++ph) {
    const int j = ph ? (127 - j0) : j0;
    const int q0 = j * 16;
    const int ntiles = (j >> 2) + 1;

    bf16x8 aq0, aq1;
    {
      const size_t qoff = ((size_t)b * NT + q0 + fr) * NH;
      aq0 = ld_frag(&qp[qoff + fo]);
      aq1 = ld_frag(&qp[qoff + 32 + fo]);
    }

    f32x4 o[4];
#pragma unroll
    for (int n = 0; n < 4; ++n) o[n] = (f32x4){0.f, 0.f, 0.f, 0.f};
    float lp[4] = {0.f, 0.f, 0.f, 0.f};

    for (int kt = w; kt < ntiles; kt += 8) {
      const int kv0 = kt * 64;

      f32x4 s[4];
#pragma unroll
      for (int n = 0; n < 4; ++n) s[n] = (f32x4){0.f, 0.f, 0.f, 0.f};
#pragma unroll
      for (int n = 0; n < 4; ++n) {
        const size_t koff = ((size_t)b*NT + kv0 + n*16 + fr) * NH + fo;
        s[n] = __builtin_amdgcn_mfma_f32_16x16x32_bf16(aq0, ld_frag(&kp[koff]), s[n], 0, 0, 0);
        s[n] = __builtin_amdgcn_mfma_f32_16x16x32_bf16(aq1, ld_frag(&kp[koff + 32]), s[n], 0, 0, 0);
      }

#pragma unroll
      for (int n = 0; n < 4; ++n)
#pragma unroll
        for (int r = 0; r < 4; ++r) s[n][r] = __expf(s[n][r] * 0.125f);

      if (kt == ntiles - 1) {   // only the last tile is causally partial
#pragma unroll
        for (int n = 0; n < 4; ++n) {
          const int col = kv0 + n*16 + fr;
#pragma unroll
          for (int r = 0; r < 4; ++r)
            if (col > q0 + rg + r) s[n][r] = 0.f;
        }
      }

#pragma unroll
      for (int r = 0; r < 4; ++r)
        lp[r] += (s[0][r] + s[1][r]) + (s[2][r] + s[3][r]);

      // P -> per-wave LDS (C-layout), read back in A-layout (same wave)
#pragma unroll
      for (int n = 0; n < 4; ++n)
#pragma unroll
        for (int r = 0; r < 4; ++r)
          Psm[w][rg + r][n*16 + fr] = f2bf(s[n][r]);

      bf16x8 pa0 = ld_frag(&Psm[w][fr][fo]);
      bf16x8 pa1 = ld_frag(&Psm[w][fr][32 + fo]);

#pragma unroll
      for (int n = 0; n < 4; ++n) {
        const size_t voff = (size_t)(n*16 + fr) * BT + (size_t)b*NT + kv0 + fo;
        o[n] = __builtin_amdgcn_mfma_f32_16x16x32_bf16(pa0, ld_frag(&vt[voff]), o[n], 0, 0, 0);
        o[n] = __builtin_amdgcn_mfma_f32_16x16x32_bf16(pa1, ld_frag(&vt[voff + 32]), o[n], 0, 0, 0);
      }
    }

    // publish per-wave partials
#pragma unroll
    for (int r = 0; r < 4; ++r) {
#pragma unroll
      for (int off = 1; off < 16; off <<= 1) lp[r] += __shfl_xor(lp[r], off);
    }
    if (fr == 0) {
#pragma unroll
      for (int r = 0; r < 4; ++r) cl[w][rg + r] = lp[r];
    }
#pragma unroll
    for (int n = 0; n < 4; ++n)
#pragma unroll
      for (int r = 0; r < 4; ++r) co[w][rg + r][n*16 + fr] = o[n][r];
    __syncthreads();

    { // merge 8 kv-split partials: plain sums (common exponent offset)
      const int row = (t >> 4) & 15, c0 = (t & 15) * 4;
      if (t < 256) {
        float l = 0.f;
#pragma unroll
        for (int ww = 0; ww < 8; ++ww) l += cl[ww][row];
        const float inv = 1.f / l;
        float4 ov = {0.f, 0.f, 0.f, 0.f};
#pragma unroll
        for (int ww = 0; ww < 8; ++ww) {
          ov.x += co[ww][row][c0+0]; ov.y += co[ww][row][c0+1];
          ov.z += co[ww][row][c0+2]; ov.w += co[ww][row][c0+3];
        }
        ov.x *= inv; ov.y *= inv; ov.z *= inv; ov.w *= inv;
        *(float4*)&out[((size_t)b*NT + q0 + row) * NH + c0] = ov;
      }
    }
    if (ph == 0) __syncthreads();
  }
}

extern "C" void kernel_launch(void* const* d_in, const int* in_sizes, int n_in,
                              void* d_out, int out_size, void* d_ws, size_t ws_size,
                              hipStream_t stream) {
  (void)in_sizes; (void)n_in; (void)out_size; (void)ws_size;
  const float* x  = (const float*)d_in[0];
  const float* Wk = (const float*)d_in[1];
  const float* Wq = (const float*)d_in[2];
  const float* Wv = (const float*)d_in[3];
  unsigned short* qkv = (unsigned short*)d_ws;                       // q,k natural + vT, 6 MB
  unsigned short* Wt  = qkv + (size_t)3 * BT * NH;                   // 384 KB

  wconv_kernel<<<48, 256, 0, stream>>>(Wk, Wq, Wv, Wt);
  proj_kernel<<<BT/32, 256, 0, stream>>>(x, Wt, qkv);
  attn_kernel<<<dim3(64, NB), 512, 0, stream>>>(qkv, (float*)d_out);
}